// Round 6
// baseline (2959.705 us; speedup 1.0000x reference)
//
#include <hip/hip_runtime.h>
#include <hip/hip_bf16.h>
#include <cmath>

// Problem: N=64, T=512, D=256, H=256 (all fp32)
//   c   = x @ Wx + b          (N,T,H)  -- parallel GEMM (phase 1, into d_out)
//   h_t = tanh(c_t + h_{t-1} @ Wh)     -- sequential scan (phase 2, in place)
//
// R6 scan: deliberate L2 streaming of Wh. R1-R5 lesson: the RA will not keep
// 128+ per-thread values live across the t-loop (sink/spill every time), and
// low-precision Wh is numerically dead (recurrence amplifies per-step error
// ~1e4x; fp16 W injects ~3e-4/step -> O(1) final error). With only 64 blocks,
// each XCD's L2 serves 8 blocks: per-step 2 MB/XCD at ~1900 B/cyc -> ~1090
// cyc/step streaming floor, BETTER than LDS BW. R1 proved streaming works
// (930 ns/step with 64 SCALAR loads); this round: pre-packed float4 layout ->
// 16 coalesced dwordx4 loads/thread/step, 16 deep in flight.

#define KDIM  256
#define HDIM  256
#define TSTEPS 512
#define NBATCH 64

__device__ __forceinline__ float fast_tanh(float s) {
    float a = fabsf(s);
    float e = __expf(-2.0f * a);
    float r = (1.0f - e) * __builtin_amdgcn_rcpf(1.0f + e);
    return s < 0.0f ? -r : r;
}

// ---------------- Phase 0: pack Wh for the scan ----------------
// w4[k*64+lane] = {Wh[k][lane], Wh[k][lane+64], Wh[k][lane+128], Wh[k][lane+192]}
// A wave reading row k hits 64 consecutive float4 -> perfect dwordx4 coalescing.
__global__ __launch_bounds__(256) void pack_w(
    const float* __restrict__ Wh, float4* __restrict__ w4)
{
    int idx  = blockIdx.x * 256 + threadIdx.x;   // 0..16383
    int k    = idx >> 6;
    int lane = idx & 63;
    const float* wr = Wh + (size_t)k * HDIM;
    float4 v;
    v.x = wr[lane];
    v.y = wr[lane + 64];
    v.z = wr[lane + 128];
    v.w = wr[lane + 192];
    w4[idx] = v;
}

// ---------------- Phase 1: c = x @ Wx + b ----------------
// 128x128 tile, 256 threads, 8x8 outputs/thread, K-chunks of 32. (unchanged)
__global__ __launch_bounds__(256, 2) void xw_gemm(
    const float* __restrict__ x,    // (32768, 256)
    const float* __restrict__ Wx,   // (256, 256)
    const float* __restrict__ bias, // (256)
    float* __restrict__ out)        // (32768, 256)
{
    __shared__ float As[32][132];   // [k][m]
    __shared__ float Bs[32][132];   // [k][n]

    const int tid = threadIdx.x;
    const int mt = tid >> 4;
    const int nt = tid & 15;
    const int m0 = blockIdx.x * 128;
    const int n0 = blockIdx.y * 128;

    float acc[8][8];
#pragma unroll
    for (int i = 0; i < 8; ++i)
#pragma unroll
        for (int j = 0; j < 8; ++j) acc[i][j] = 0.f;

    for (int kc = 0; kc < KDIM; kc += 32) {
        {
            const int k4 = tid & 7;
            const int mr = tid >> 3;
#pragma unroll
            for (int p = 0; p < 4; ++p) {
                int mrow = mr + 32 * p;
                float4 v = *(const float4*)&x[(size_t)(m0 + mrow) * KDIM + kc + 4 * k4];
                As[4 * k4 + 0][mrow] = v.x;
                As[4 * k4 + 1][mrow] = v.y;
                As[4 * k4 + 2][mrow] = v.z;
                As[4 * k4 + 3][mrow] = v.w;
            }
        }
        {
            const int nn = 4 * (tid & 31);
            const int kr = tid >> 5;
#pragma unroll
            for (int p = 0; p < 4; ++p) {
                int krow = kr + 8 * p;
                float4 v = *(const float4*)&Wx[(size_t)(kc + krow) * HDIM + n0 + nn];
                *(float4*)&Bs[krow][nn] = v;
            }
        }
        __syncthreads();

#pragma unroll 4
        for (int k = 0; k < 32; ++k) {
            float4 a0 = *(const float4*)&As[k][8 * mt];
            float4 a1 = *(const float4*)&As[k][8 * mt + 4];
            float4 b0 = *(const float4*)&Bs[k][8 * nt];
            float4 b1 = *(const float4*)&Bs[k][8 * nt + 4];
            float av[8] = {a0.x, a0.y, a0.z, a0.w, a1.x, a1.y, a1.z, a1.w};
            float bv[8] = {b0.x, b0.y, b0.z, b0.w, b1.x, b1.y, b1.z, b1.w};
#pragma unroll
            for (int i = 0; i < 8; ++i)
#pragma unroll
                for (int j = 0; j < 8; ++j) acc[i][j] += av[i] * bv[j];
        }
        __syncthreads();
    }

    float4 bj0 = *(const float4*)&bias[n0 + 8 * nt];
    float4 bj1 = *(const float4*)&bias[n0 + 8 * nt + 4];
    float bb[8] = {bj0.x, bj0.y, bj0.z, bj0.w, bj1.x, bj1.y, bj1.z, bj1.w};
#pragma unroll
    for (int i = 0; i < 8; ++i) {
        float4 v0, v1;
        v0.x = acc[i][0] + bb[0]; v0.y = acc[i][1] + bb[1];
        v0.z = acc[i][2] + bb[2]; v0.w = acc[i][3] + bb[3];
        v1.x = acc[i][4] + bb[4]; v1.y = acc[i][5] + bb[5];
        v1.z = acc[i][6] + bb[6]; v1.w = acc[i][7] + bb[7];
        float* o = &out[(size_t)(m0 + 8 * mt + i) * HDIM + n0 + 8 * nt];
        *(float4*)&o[0] = v0;
        *(float4*)&o[4] = v1;
    }
}

// ---------------- Phase 2: sequential scan ----------------
// 1024 threads = 16 waves, 1 block/CU. Wave g owns k in [16g,16g+16); lane
// owns cols {lane+64c, c<4}. Per step/thread: 16 global dwordx4 (w4 rows,
// L2-resident), 4 broadcast ds_read_b128 (h), 64 v_fmac, 4 ds_add_f32 into a
// double-buffered accumulator pre-seeded with c_t.
__global__
__attribute__((amdgpu_flat_work_group_size(1024, 1024), amdgpu_waves_per_eu(4, 4)))
void rnn_scan(
    const float* __restrict__ h0,   // (64, 256)
    const float4* __restrict__ w4,  // (256*64) packed Wh
    float* __restrict__ out)        // (64, 512, 256): holds c, overwritten by h
{
    const int r    = blockIdx.x;
    const int tid  = threadIdx.x;
    const int lane = tid & 63;
    const int g    = tid >> 6;      // wave = k-group, k in [16g,16g+16)

    __shared__ float hbuf[256];
    __shared__ float accb[2][256];

    const float4* wg = w4 + (size_t)(16 * g) * 64 + lane;
    float* outr = out + (size_t)r * TSTEPS * HDIM;

    if (tid < 256) {
        hbuf[tid]    = h0[(size_t)r * HDIM + tid];
        accb[0][tid] = outr[tid];    // pre-seed step-0 accumulator with c_0
    }
    __syncthreads();

    const float4* hv = (const float4*)(hbuf + 16 * g);

#pragma unroll 1
    for (int t = 0; t < TSTEPS; ++t) {
        float* cur = accb[t & 1];
        float* nxt = accb[(t & 1) ^ 1];

        // Prefetch c_{t+1} (used after the barrier; deepest in the queue).
        int tn = (t + 1 < TSTEPS) ? t + 1 : t;
        float cnext = 0.f;
        if (tid < 256) cnext = outr[(size_t)tn * HDIM + tid];

        // Issue all 16 W-row loads (coalesced dwordx4, L2-resident).
        float4 w[16];
#pragma unroll
        for (int i = 0; i < 16; ++i) w[i] = wg[(size_t)i * 64];

        // h fragment for this wave's k-range (broadcast reads).
        float4 h4[4];
#pragma unroll
        for (int q = 0; q < 4; ++q) h4[q] = hv[q];

        // acc_c = sum_{i<16} h[16g+i] * Wh[16g+i][lane+64c]
        float a0 = 0.f, a1 = 0.f, a2 = 0.f, a3 = 0.f;
#pragma unroll
        for (int q = 0; q < 4; ++q) {
            float hx = h4[q].x, hy = h4[q].y, hz = h4[q].z, hw = h4[q].w;
            a0 += hx * w[4*q+0].x; a1 += hx * w[4*q+0].y; a2 += hx * w[4*q+0].z; a3 += hx * w[4*q+0].w;
            a0 += hy * w[4*q+1].x; a1 += hy * w[4*q+1].y; a2 += hy * w[4*q+1].z; a3 += hy * w[4*q+1].w;
            a0 += hz * w[4*q+2].x; a1 += hz * w[4*q+2].y; a2 += hz * w[4*q+2].z; a3 += hz * w[4*q+2].w;
            a0 += hw * w[4*q+3].x; a1 += hw * w[4*q+3].y; a2 += hw * w[4*q+3].z; a3 += hw * w[4*q+3].w;
        }

        atomicAdd(&cur[lane],       a0);   // ds_add_f32, 2 lanes/bank: free
        atomicAdd(&cur[lane + 64],  a1);
        atomicAdd(&cur[lane + 128], a2);
        atomicAdd(&cur[lane + 192], a3);
        __syncthreads();

        if (tid < 256) {
            float hn = fast_tanh(cur[tid]);
            outr[(size_t)t * HDIM + tid] = hn;   // in-place; c_t consumed
            hbuf[tid] = hn;                      // FMA reads done (barrier)
            nxt[tid]  = cnext;                   // seed next accumulator
        }
        __syncthreads();
    }
}

extern "C" void kernel_launch(void* const* d_in, const int* in_sizes, int n_in,
                              void* d_out, int out_size, void* d_ws, size_t ws_size,
                              hipStream_t stream) {
    const float* x  = (const float*)d_in[0];   // (64,512,256)
    const float* h0 = (const float*)d_in[1];   // (64,256)
    const float* Wx = (const float*)d_in[2];   // (256,256)
    const float* Wh = (const float*)d_in[3];   // (256,256)
    const float* b  = (const float*)d_in[4];   // (256)
    float* out = (float*)d_out;                // (64,512,256)
    float4* w4 = (float4*)d_ws;                // 256 KB packed Wh

    pack_w<<<64, 256, 0, stream>>>(Wh, w4);

    dim3 g1(32768 / 128, HDIM / 128);
    xw_gemm<<<g1, 256, 0, stream>>>(x, Wx, b, out);

    rnn_scan<<<NBATCH, 1024, 0, stream>>>(h0, w4, out);
}